// Round 7
// baseline (291.175 us; speedup 1.0000x reference)
//
#include <hip/hip_runtime.h>
#include <hip/hip_bf16.h>

typedef __attribute__((ext_vector_type(8))) short bf16x8_t;
typedef __attribute__((ext_vector_type(4))) float f32x4_t;
typedef __attribute__((ext_vector_type(8))) unsigned short u16x8_t;

__device__ inline unsigned short f2bf(float x) {
    union { float f; unsigned int u; } v; v.f = x;
    unsigned int r = v.u + 0x7FFFu + ((v.u >> 16) & 1u);
    return (unsigned short)(r >> 16);
}

__device__ inline void gl_lds16(const void* g, void* l) {
    __builtin_amdgcn_global_load_lds(
        (const __attribute__((address_space(1))) void*)g,
        (__attribute__((address_space(3))) void*)l, 16, 0, 0);
}

// ------------- fused f32 -> bf16 convert for both tensors ------------------
__global__ __launch_bounds__(256) void f32_to_bf16_2(
    const float* __restrict__ za, const float* __restrict__ zb,
    unsigned short* __restrict__ da, unsigned short* __restrict__ db, int n8) {
    int stride = gridDim.x * blockDim.x;
    int total = 2 * n8;
    for (int i = blockIdx.x * blockDim.x + threadIdx.x; i < total; i += stride) {
        const float* s = (i < n8) ? za : zb;
        unsigned short* d = (i < n8) ? da : db;
        int j = (i < n8) ? i : i - n8;
        const float4* p = (const float4*)(s + (size_t)j * 8);
        float4 a = p[0], b = p[1];
        u16x8_t v;
        v[0] = f2bf(a.x); v[1] = f2bf(a.y); v[2] = f2bf(a.z); v[3] = f2bf(a.w);
        v[4] = f2bf(b.x); v[5] = f2bf(b.y); v[6] = f2bf(b.z); v[7] = f2bf(b.w);
        *(u16x8_t*)(d + (size_t)j * 8) = v;
    }
}

// ------ merged 256x256-tile GEMM+LSE: blocks 0..647 overlap, 648..1223 tile -
// BK=64, 2-slot LDS ring (64KB/slot), stage t+1 at t's head, one
// lgkm0+vmcnt0+barrier per K64-tile (full-tile flight span covers latency).
// Rows are 128B: one full cache line per row per tile (half the transactions
// of BK=32). Swizzle: 16B-chunk phys = logical ^ (row&7): inverse on global
// source, forward on ds_read, linear LDS dest (rule 21). 12 K-tiles.
// ws float layout:
// [0) rs_ov 18432 | [18432) cs_ov 18432 | [36864) dg_ov 18432
// [55296) rs_t 36864 | [92160) cs_t 36864 | [129024) dg_t 36864 -> 165888
__global__ __launch_bounds__(512, 2) void gemm256_lse_all(
    const unsigned short* __restrict__ z1b, const unsigned short* __restrict__ z2b,
    float* __restrict__ ws) {
    const int tid  = threadIdx.x;
    const int lane = tid & 63;
    const int w    = tid >> 6;        // 0..7
    const int wM   = w >> 2;          // 0..1  (rows: wM*128)
    const int wN   = w & 3;           // 0..3  (cols: wN*64)
    const int lr   = lane & 15;
    const int lg   = lane >> 4;       // 0..3

    // T1: XCD-aware bijective swizzle over 1224 = 8*153 blocks
    const int bid = blockIdx.x;
    const int lb  = (bid & 7) * 153 + (bid >> 3);

    int M, TM, batch, rem;
    float inv_tau;
    float *rs, *cs, *dg;
    bool ov = (lb < 648);
    if (ov) {
        M = 2304; TM = 9; inv_tau = 1.0f / 0.07f;
        rs = ws; cs = ws + 18432; dg = ws + 36864;
        batch = lb / 81; rem = lb - batch * 81;
    } else {
        M = 576; TM = 3; inv_tau = 1.0f / 0.2f;
        rs = ws + 55296; cs = ws + 92160; dg = ws + 129024;
        int tl = lb - 648;
        batch = tl / 9; rem = tl - batch * 9;
    }
    const int brow = rem / TM;
    const int bcol = rem - brow * TM;

    // 2 slots x (A[256][64] + B[256][64]) = 2 x 32768 ushorts = 128 KiB
    __shared__ unsigned short smem[65536];
    __shared__ int offA[256], offB[256];

    if (tid < 256) {
        int r = brow * 256 + tid;
        int off;
        if (ov) {
            int b = r / 288, rm = r % 288, h = rm / 12, j = rm % 12;
            off = ((b * 8 + batch) * 576 + h * 24 + 12 + j) * 768;
        } else {
            off = ((r < M) ? (batch * 576 + r) : (batch * 576)) * 768;
        }
        offA[tid] = off;
    } else {
        int c = bcol * 256 + (tid - 256);
        int off;
        if (ov) {
            int b = c / 288, rm = c % 288, h = rm / 12, j = rm % 12;
            off = ((b * 8 + ((batch + 1) & 7)) * 576 + h * 24 + j) * 768;
        } else {
            off = ((c < M) ? (batch * 576 + c) : (batch * 576)) * 768;
        }
        offB[tid - 256] = off;
    }
    __syncthreads();

    // staging: wave w stages A rows [w*32, w*32+32) (4 gl_lds x 8 rows), same
    // for B. lane covers row base+(lane>>3), phys 16B-chunk lane&7; source
    // fetches logical chunk (lane&7)^(row&7), row&7 == lane>>3.
    const int lrow8 = lane >> 3;
    const int cswz  = (((lane & 7) ^ lrow8) << 3);
    int sA[4], sB[4];
#pragma unroll
    for (int ra = 0; ra < 4; ++ra) {
        sA[ra] = offA[w * 32 + ra * 8 + lrow8] + cswz;
        sB[ra] = offB[w * 32 + ra * 8 + lrow8] + cswz;
    }

    // swizzled read offsets (ushort units within a slot); logical chunk
    // 4*h+lg of row, phys = logical ^ (row&7), row&7 == lr&7.
    int aoff[2][8], boff[2][4];
#pragma unroll
    for (int h = 0; h < 2; ++h) {
#pragma unroll
        for (int i = 0; i < 8; ++i) {
            int row = wM * 128 + i * 16 + lr;
            aoff[h][i] = row * 64 + ((((4 * h + lg)) ^ (lr & 7)) << 3);
        }
#pragma unroll
        for (int j = 0; j < 4; ++j) {
            int row = wN * 64 + j * 16 + lr;
            boff[h][j] = 16384 + row * 64 + ((((4 * h + lg)) ^ (lr & 7)) << 3);
        }
    }

    f32x4_t acc[8][4];
#pragma unroll
    for (int i = 0; i < 8; ++i)
#pragma unroll
        for (int j = 0; j < 4; ++j) acc[i][j] = (f32x4_t){0.f, 0.f, 0.f, 0.f};

#define SA_(T) do { \
    const int sl_ = ((T) & 1) * 32768; const int k0_ = (T) * 64; \
    _Pragma("unroll") \
    for (int ra = 0; ra < 4; ++ra) \
        gl_lds16(z1b + sA[ra] + k0_, &smem[sl_ + (w * 32 + ra * 8) * 64]); \
} while (0)
#define SB_(T) do { \
    const int sl_ = ((T) & 1) * 32768; const int k0_ = (T) * 64; \
    _Pragma("unroll") \
    for (int ra = 0; ra < 4; ++ra) \
        gl_lds16(z2b + sB[ra] + k0_, &smem[sl_ + 16384 + (w * 32 + ra * 8) * 64]); \
} while (0)

// One K64-tile: stage t+1 at head (slot (t+1)&1 is free: its readers finished
// before the barrier that ended tile t-1), read+MFMA two K32 halves, then
// lgkm0 (cross-wave overwrite guard) + vmcnt0 (t+1 landed; full-tile span)
// + one barrier.
#define TILE(T, DS) do { \
    const int sl_ = ((T) & 1) * 32768; \
    if (DS) SA_((T) + 1); \
    bf16x8_t af[8], bf[4]; \
    _Pragma("unroll") \
    for (int i = 0; i < 8; ++i) af[i] = *(const bf16x8_t*)&smem[sl_ + aoff[0][i]]; \
    _Pragma("unroll") \
    for (int j = 0; j < 4; ++j) bf[j] = *(const bf16x8_t*)&smem[sl_ + boff[0][j]]; \
    __builtin_amdgcn_s_setprio(1); \
    _Pragma("unroll") \
    for (int i = 0; i < 8; ++i) \
        _Pragma("unroll") \
        for (int j = 0; j < 4; ++j) \
            acc[i][j] = __builtin_amdgcn_mfma_f32_16x16x32_bf16( \
                af[i], bf[j], acc[i][j], 0, 0, 0); \
    __builtin_amdgcn_s_setprio(0); \
    if (DS) SB_((T) + 1); \
    _Pragma("unroll") \
    for (int i = 0; i < 8; ++i) af[i] = *(const bf16x8_t*)&smem[sl_ + aoff[1][i]]; \
    _Pragma("unroll") \
    for (int j = 0; j < 4; ++j) bf[j] = *(const bf16x8_t*)&smem[sl_ + boff[1][j]]; \
    __builtin_amdgcn_s_setprio(1); \
    _Pragma("unroll") \
    for (int i = 0; i < 8; ++i) \
        _Pragma("unroll") \
        for (int j = 0; j < 4; ++j) \
            acc[i][j] = __builtin_amdgcn_mfma_f32_16x16x32_bf16( \
                af[i], bf[j], acc[i][j], 0, 0, 0); \
    __builtin_amdgcn_s_setprio(0); \
    if ((T) < 11) { \
        asm volatile("s_waitcnt lgkmcnt(0)" ::: "memory"); \
        asm volatile("s_waitcnt vmcnt(0)" ::: "memory"); \
        __builtin_amdgcn_s_barrier(); \
    } \
} while (0)

    SA_(0); SB_(0);
    asm volatile("s_waitcnt vmcnt(0)" ::: "memory");
    __builtin_amdgcn_s_barrier();

#pragma unroll 2
    for (int t = 0; t < 10; ++t) TILE(t, true);
    TILE(10, true);     // stages tile 11
    TILE(11, false);
#undef TILE
#undef SA_
#undef SB_

    // Epilogue: L = acc*inv_tau; exp row/col partial sums; diag.
    const int rowbase = brow * 256 + wM * 128;
    const int colbase = bcol * 256 + wN * 64;
    float colacc[4] = {0.f, 0.f, 0.f, 0.f};
#pragma unroll
    for (int i = 0; i < 8; ++i) {
#pragma unroll
        for (int reg = 0; reg < 4; ++reg) {
            int row = rowbase + i * 16 + lg * 4 + reg;
            bool rv = row < M;
            float rp = 0.f;
#pragma unroll
            for (int j = 0; j < 4; ++j) {
                int col = colbase + j * 16 + lr;
                float L = acc[i][j][reg] * inv_tau;
                float e = (rv && (col < M)) ? __expf(L) : 0.f;
                rp += e;
                colacc[j] += e;
                if (rv && row == col) dg[batch * M + row] = L;
            }
#pragma unroll
            for (int s = 1; s < 16; s <<= 1) rp += __shfl_xor(rp, s);
            if (lr == 0 && rv) atomicAdd(&rs[batch * M + row], rp);
        }
    }
#pragma unroll
    for (int j = 0; j < 4; ++j) {
        float cv = colacc[j];
        cv += __shfl_xor(cv, 16);
        cv += __shfl_xor(cv, 32);
        int col = colbase + j * 16 + lr;
        if (lg == 0 && col < M) atomicAdd(&cs[batch * M + col], cv);
    }
}

// ---------------- fallback path (R1, convert-in-flight, verified) ----------
template <int MODE>
__global__ __launch_bounds__(256) void fused_gemm_lse(
    const float* __restrict__ z1, const float* __restrict__ z2,
    float* __restrict__ rowsum, float* __restrict__ colsum,
    float* __restrict__ diag) {
    constexpr int M = (MODE == 0) ? 2304 : 576;
    constexpr float inv_tau = (MODE == 0) ? (1.0f / 0.07f) : (1.0f / 0.2f);

    const int tid  = threadIdx.x;
    const int lane = tid & 63;
    const int w    = tid >> 6;
    const int wM   = w >> 1;
    const int wN   = w & 1;
    const int lr   = lane & 15;
    const int lg   = lane >> 4;
    const int brow = blockIdx.y, bcol = blockIdx.x, batch = blockIdx.z;

    __shared__ unsigned short lA[128][72];
    __shared__ unsigned short lB[128][72];
    __shared__ int offA[128];
    __shared__ int offB[128];

    if (tid < 128) {
        int r = brow * 128 + tid;
        int off;
        if (MODE == 0) {
            int b = r / 288, rem = r % 288;
            int h = rem / 12, j = rem % 12;
            off = ((b * 8 + batch) * 576 + h * 24 + 12 + j) * 768;
        } else {
            off = (r < M) ? (batch * 576 + r) * 768 : -1;
        }
        offA[tid] = off;
    } else {
        int c = bcol * 128 + (tid - 128);
        int off;
        if (MODE == 0) {
            int b = c / 288, rem = c % 288;
            int h = rem / 12, j = rem % 12;
            off = ((b * 8 + ((batch + 1) & 7)) * 576 + h * 24 + j) * 768;
        } else {
            off = (c < M) ? (batch * 576 + c) * 768 : -1;
        }
        offB[tid - 128] = off;
    }
    __syncthreads();

    f32x4_t acc[4][4];
#pragma unroll
    for (int i = 0; i < 4; ++i)
#pragma unroll
        for (int j = 0; j < 4; ++j) acc[i][j] = (f32x4_t){0.f, 0.f, 0.f, 0.f};

    for (int kt = 0; kt < 12; ++kt) {
        const int k0 = kt * 64;
#pragma unroll
        for (int rr = 0; rr < 8; ++rr) {
            int f   = tid + (rr << 8);
            int row = f >> 4;
            int c4  = f & 15;
            int oA = offA[row], oB = offB[row];
            float4 va = make_float4(0.f, 0.f, 0.f, 0.f);
            float4 vb = make_float4(0.f, 0.f, 0.f, 0.f);
            if (oA >= 0) va = *(const float4*)(z1 + oA + k0 + (c4 << 2));
            if (oB >= 0) vb = *(const float4*)(z2 + oB + k0 + (c4 << 2));
            ushort4 sa, sb;
            sa.x = f2bf(va.x); sa.y = f2bf(va.y); sa.z = f2bf(va.z); sa.w = f2bf(va.w);
            sb.x = f2bf(vb.x); sb.y = f2bf(vb.y); sb.z = f2bf(vb.z); sb.w = f2bf(vb.w);
            *(ushort4*)&lA[row][c4 << 2] = sa;
            *(ushort4*)&lB[row][c4 << 2] = sb;
        }
        __syncthreads();
#pragma unroll
        for (int kk = 0; kk < 64; kk += 32) {
            bf16x8_t av[4], bv[4];
#pragma unroll
            for (int i = 0; i < 4; ++i) {
                av[i] = *(const bf16x8_t*)&lA[wM * 64 + i * 16 + lr][kk + lg * 8];
                bv[i] = *(const bf16x8_t*)&lB[wN * 64 + i * 16 + lr][kk + lg * 8];
            }
#pragma unroll
            for (int i = 0; i < 4; ++i)
#pragma unroll
                for (int j = 0; j < 4; ++j)
                    acc[i][j] = __builtin_amdgcn_mfma_f32_16x16x32_bf16(
                        av[i], bv[j], acc[i][j], 0, 0, 0);
        }
        __syncthreads();
    }

    const int rowbase = brow * 128 + wM * 64;
    const int colbase = bcol * 128 + wN * 64;
    float colacc[4] = {0.f, 0.f, 0.f, 0.f};
#pragma unroll
    for (int i = 0; i < 4; ++i) {
#pragma unroll
        for (int reg = 0; reg < 4; ++reg) {
            int row = rowbase + i * 16 + lg * 4 + reg;
            bool rv = row < M;
            float rp = 0.f;
#pragma unroll
            for (int j = 0; j < 4; ++j) {
                int col = colbase + j * 16 + lr;
                float L = acc[i][j][reg] * inv_tau;
                float e = (rv && (col < M)) ? __expf(L) : 0.f;
                rp += e;
                colacc[j] += e;
                if (rv && row == col) diag[batch * M + row] = L;
            }
#pragma unroll
            for (int s = 1; s < 16; s <<= 1) rp += __shfl_xor(rp, s);
            if (lr == 0 && rv) atomicAdd(&rowsum[batch * M + row], rp);
        }
    }
#pragma unroll
    for (int j = 0; j < 4; ++j) {
        float c = colacc[j];
        c += __shfl_xor(c, 16);
        c += __shfl_xor(c, 32);
        int col = colbase + j * 16 + lr;
        if (lg == 0 && col < M) atomicAdd(&colsum[batch * M + col], c);
    }
}

__global__ void finalize_kernel(const float* __restrict__ ws, float* __restrict__ out) {
    const float* rs_ov = ws;
    const float* cs_ov = ws + 18432;
    const float* dg_ov = ws + 36864;
    const float* rs_t  = ws + 55296;
    const float* cs_t  = ws + 92160;
    const float* dg_t  = ws + 129024;
    float s_ov = 0.f, s_t = 0.f;
    for (int i = threadIdx.x; i < 18432; i += 256)
        s_ov += logf(rs_ov[i]) + logf(cs_ov[i]) - 2.f * dg_ov[i];
    for (int i = threadIdx.x; i < 36864; i += 256)
        s_t += logf(rs_t[i]) + logf(cs_t[i]) - 2.f * dg_t[i];
#pragma unroll
    for (int s = 1; s < 64; s <<= 1) {
        s_ov += __shfl_xor(s_ov, s);
        s_t  += __shfl_xor(s_t, s);
    }
    __shared__ float red[2][4];
    int w = threadIdx.x >> 6;
    if ((threadIdx.x & 63) == 0) { red[0][w] = s_ov; red[1][w] = s_t; }
    __syncthreads();
    if (threadIdx.x == 0) {
        float a = red[0][0] + red[0][1] + red[0][2] + red[0][3];
        float b = red[1][0] + red[1][1] + red[1][2] + red[1][3];
        out[0] = 0.5f * a / 18432.f + 0.05f * b / 36864.f;
    }
}

extern "C" void kernel_launch(void* const* d_in, const int* in_sizes, int n_in,
                              void* d_out, int out_size, void* d_ws, size_t ws_size,
                              hipStream_t stream) {
    const float* z1 = (const float*)d_in[0];
    const float* z2 = (const float*)d_in[1];
    float* out = (float*)d_out;
    float* ws  = (float*)d_ws;

    const size_t N_ELEM = (size_t)64 * 576 * 768;
    const size_t ACC_B  = 165888 * sizeof(float);
    const size_t BF_B   = N_ELEM * 2;
    const size_t NEED   = ACC_B + 2 * BF_B;

    hipMemsetAsync(d_ws, 0, ACC_B, stream);
    dim3 blk256(256, 1, 1);

    if (ws_size >= NEED) {
        unsigned short* z1b = (unsigned short*)((char*)d_ws + ACC_B);
        unsigned short* z2b = z1b + N_ELEM;
        int n8 = (int)(N_ELEM / 8);
        f32_to_bf16_2<<<2048, blk256, 0, stream>>>(z1, z2, z1b, z2b, n8);
        gemm256_lse_all<<<1224, 512, 0, stream>>>(z1b, z2b, ws);
    } else {
        fused_gemm_lse<0><<<dim3(18, 18, 8), blk256, 0, stream>>>(
            z1, z2, ws, ws + 18432, ws + 36864);
        fused_gemm_lse<1><<<dim3(5, 5, 64), blk256, 0, stream>>>(
            z1, z2, ws + 55296, ws + 92160, ws + 129024);
    }
    finalize_kernel<<<1, 256, 0, stream>>>(ws, out);
}

// Round 8
// 279.355 us; speedup vs baseline: 1.0423x; 1.0423x over previous
//
#include <hip/hip_runtime.h>
#include <hip/hip_bf16.h>

typedef __attribute__((ext_vector_type(8))) short bf16x8_t;
typedef __attribute__((ext_vector_type(4))) float f32x4_t;
typedef __attribute__((ext_vector_type(8))) unsigned short u16x8_t;

__device__ inline unsigned short f2bf(float x) {
    union { float f; unsigned int u; } v; v.f = x;
    unsigned int r = v.u + 0x7FFFu + ((v.u >> 16) & 1u);
    return (unsigned short)(r >> 16);
}

__device__ inline void gl_lds16(const void* g, void* l) {
    __builtin_amdgcn_global_load_lds(
        (const __attribute__((address_space(1))) void*)g,
        (__attribute__((address_space(3))) void*)l, 16, 0, 0);
}

// ------------- fused f32 -> bf16 convert for both tensors ------------------
__global__ __launch_bounds__(256) void f32_to_bf16_2(
    const float* __restrict__ za, const float* __restrict__ zb,
    unsigned short* __restrict__ da, unsigned short* __restrict__ db, int n8) {
    int stride = gridDim.x * blockDim.x;
    int total = 2 * n8;
    for (int i = blockIdx.x * blockDim.x + threadIdx.x; i < total; i += stride) {
        const float* s = (i < n8) ? za : zb;
        unsigned short* d = (i < n8) ? da : db;
        int j = (i < n8) ? i : i - n8;
        const float4* p = (const float4*)(s + (size_t)j * 8);
        float4 a = p[0], b = p[1];
        u16x8_t v;
        v[0] = f2bf(a.x); v[1] = f2bf(a.y); v[2] = f2bf(a.z); v[3] = f2bf(a.w);
        v[4] = f2bf(b.x); v[5] = f2bf(b.y); v[6] = f2bf(b.z); v[7] = f2bf(b.w);
        *(u16x8_t*)(d + (size_t)j * 8) = v;
    }
}

// ---- merged 128x128-tile GEMM+LSE, 4 waves, BK=32, 3-slot ring ------------
// blocks (after XCD swizzle): lb 0..2591 overlap (18x18x8), 2592..4191 tile
// (5x5x64, 640-padded).  LDS slot s (16KB): A[128][32] at s*8192,
// B[128][32] at s*8192+4096 (ushorts); 3 slots = 48KB -> 3 blocks/CU.
// Ring: stage t+2 during t; steady vmcnt(4) (never drains in-loop), tail 4/0.
// Swizzle: 16B-chunk phys = logical ^ ((row>>1)&3); inverse on global source,
// forward on ds_read, linear LDS dest (rule 21; R5-verified 0 conflicts).
// One barrier + one counted wait per K32-step; sibling blocks cover stalls.
// ws float layout:
// [0) rs_ov 18432 | [18432) cs_ov 18432 | [36864) dg_ov 18432
// [55296) rs_t 36864 | [92160) cs_t 36864 | [129024) dg_t 36864 -> 165888
__global__ __launch_bounds__(256, 3) void gemm128_lse_all(
    const unsigned short* __restrict__ z1b, const unsigned short* __restrict__ z2b,
    float* __restrict__ ws) {
    const int tid  = threadIdx.x;
    const int lane = tid & 63;
    const int w    = tid >> 6;        // 0..3
    const int wM   = w >> 1;          // 0..1 (rows: wM*64)
    const int wN   = w & 1;           // 0..1 (cols: wN*64)
    const int lr   = lane & 15;
    const int lg   = lane >> 4;       // 0..3

    // T1: XCD-aware bijective swizzle over 4192 = 8*524 blocks
    const int bid = blockIdx.x;
    const int lb  = (bid & 7) * 524 + (bid >> 3);

    int M, TM, batch, rem;
    float inv_tau;
    float *rs, *cs, *dg;
    bool ov = (lb < 2592);
    if (ov) {
        M = 2304; TM = 18; inv_tau = 1.0f / 0.07f;
        rs = ws; cs = ws + 18432; dg = ws + 36864;
        batch = lb / 324; rem = lb - batch * 324;
    } else {
        M = 576; TM = 5; inv_tau = 1.0f / 0.2f;
        rs = ws + 55296; cs = ws + 92160; dg = ws + 129024;
        int tl = lb - 2592;
        batch = tl / 25; rem = tl - batch * 25;
    }
    const int brow = rem / TM;
    const int bcol = rem - brow * TM;

    __shared__ unsigned short smem[24576];   // 3 slots x 8192 ushorts = 48 KiB
    __shared__ int offA[128], offB[128];

    if (tid < 128) {
        int r = brow * 128 + tid;
        int off;
        if (ov) {
            int b = r / 288, rm = r % 288, h = rm / 12, j = rm % 12;
            off = ((b * 8 + batch) * 576 + h * 24 + 12 + j) * 768;
        } else {
            off = ((r < M) ? (batch * 576 + r) : (batch * 576)) * 768;
        }
        offA[tid] = off;
    } else {
        int c = bcol * 128 + (tid - 128);
        int off;
        if (ov) {
            int b = c / 288, rm = c % 288, h = rm / 12, j = rm % 12;
            off = ((b * 8 + ((batch + 1) & 7)) * 576 + h * 24 + j) * 768;
        } else {
            off = ((c < M) ? (batch * 576 + c) : (batch * 576)) * 768;
        }
        offB[tid - 128] = off;
    }
    __syncthreads();

    // staging: load r covers rows r*64 + w*16 + (lane>>2), phys chunk lane&3;
    // source fetches logical chunk (lane&3) ^ ((row>>1)&3). LDS dest linear.
    int srcA[2], srcB[2];
#pragma unroll
    for (int r = 0; r < 2; ++r) {
        int row = r * 64 + w * 16 + (lane >> 2);
        int cs_ = (((lane & 3) ^ ((row >> 1) & 3)) << 3);
        srcA[r] = offA[row] + cs_;
        srcB[r] = offB[row] + cs_;
    }

    // swizzled read offsets (ushort units within a slot)
    int aoff[4], boff[4];
#pragma unroll
    for (int i = 0; i < 4; ++i) {
        int ra = wM * 64 + i * 16 + lr;
        aoff[i] = ra * 32 + ((lg ^ ((ra >> 1) & 3)) << 3);
        int rb = wN * 64 + i * 16 + lr;
        boff[i] = 4096 + rb * 32 + ((lg ^ ((rb >> 1) & 3)) << 3);
    }

    f32x4_t acc[4][4];
#pragma unroll
    for (int i = 0; i < 4; ++i)
#pragma unroll
        for (int j = 0; j < 4; ++j) acc[i][j] = (f32x4_t){0.f, 0.f, 0.f, 0.f};

#define STG(T) do { \
    const int sl_ = ((T) % 3) * 8192; const int k0_ = (T) * 32; \
    gl_lds16(z1b + srcA[0] + k0_, &smem[sl_ + (w * 16) * 32]); \
    gl_lds16(z1b + srcA[1] + k0_, &smem[sl_ + (64 + w * 16) * 32]); \
    gl_lds16(z2b + srcB[0] + k0_, &smem[sl_ + 4096 + (w * 16) * 32]); \
    gl_lds16(z2b + srcB[1] + k0_, &smem[sl_ + 4096 + (64 + w * 16) * 32]); \
} while (0)

// One K32-step: counted wait (tile T landed chip-wide after barrier), stage
// T+2 into the slot freed by T-1, then 8 ds_read + 16 MFMA (compiler
// interleaves via fine lgkmcnt; no sched_barrier pinning).
#define TILE(T, VMSTR, DS) do { \
    asm volatile("s_waitcnt " VMSTR ::: "memory"); \
    __builtin_amdgcn_s_barrier(); \
    if (DS) STG((T) + 2); \
    const int sl_ = ((T) % 3) * 8192; \
    bf16x8_t av[4], bv[4]; \
    _Pragma("unroll") \
    for (int i = 0; i < 4; ++i) av[i] = *(const bf16x8_t*)&smem[sl_ + aoff[i]]; \
    _Pragma("unroll") \
    for (int j = 0; j < 4; ++j) bv[j] = *(const bf16x8_t*)&smem[sl_ + boff[j]]; \
    __builtin_amdgcn_s_setprio(1); \
    _Pragma("unroll") \
    for (int i = 0; i < 4; ++i) \
        _Pragma("unroll") \
        for (int j = 0; j < 4; ++j) \
            acc[i][j] = __builtin_amdgcn_mfma_f32_16x16x32_bf16( \
                av[i], bv[j], acc[i][j], 0, 0, 0); \
    __builtin_amdgcn_s_setprio(0); \
} while (0)

    STG(0); STG(1);                       // 8 outstanding

#pragma unroll 3
    for (int t = 0; t < 21; ++t) TILE(t, "vmcnt(4)", true);
    TILE(21, "vmcnt(4)", true);           // stages tile 23
    TILE(22, "vmcnt(4)", false);
    TILE(23, "vmcnt(0)", false);
#undef TILE
#undef STG

    // Epilogue: L = acc*inv_tau; exp row/col partial sums; diag.
    const int rowbase = brow * 128 + wM * 64;
    const int colbase = bcol * 128 + wN * 64;
    float colacc[4] = {0.f, 0.f, 0.f, 0.f};
#pragma unroll
    for (int i = 0; i < 4; ++i) {
#pragma unroll
        for (int reg = 0; reg < 4; ++reg) {
            int row = rowbase + i * 16 + lg * 4 + reg;
            bool rv = row < M;
            float rp = 0.f;
#pragma unroll
            for (int j = 0; j < 4; ++j) {
                int col = colbase + j * 16 + lr;
                float L = acc[i][j][reg] * inv_tau;
                float e = (rv && (col < M)) ? __expf(L) : 0.f;
                rp += e;
                colacc[j] += e;
                if (rv && row == col) dg[batch * M + row] = L;
            }
#pragma unroll
            for (int s = 1; s < 16; s <<= 1) rp += __shfl_xor(rp, s);
            if (lr == 0 && rv) atomicAdd(&rs[batch * M + row], rp);
        }
    }
#pragma unroll
    for (int j = 0; j < 4; ++j) {
        float cv = colacc[j];
        cv += __shfl_xor(cv, 16);
        cv += __shfl_xor(cv, 32);
        int col = colbase + j * 16 + lr;
        if (lg == 0 && col < M) atomicAdd(&cs[batch * M + col], cv);
    }
}

// ---------------- fallback path (R1, convert-in-flight, verified) ----------
template <int MODE>
__global__ __launch_bounds__(256) void fused_gemm_lse(
    const float* __restrict__ z1, const float* __restrict__ z2,
    float* __restrict__ rowsum, float* __restrict__ colsum,
    float* __restrict__ diag) {
    constexpr int M = (MODE == 0) ? 2304 : 576;
    constexpr float inv_tau = (MODE == 0) ? (1.0f / 0.07f) : (1.0f / 0.2f);

    const int tid  = threadIdx.x;
    const int lane = tid & 63;
    const int w    = tid >> 6;
    const int wM   = w >> 1;
    const int wN   = w & 1;
    const int lr   = lane & 15;
    const int lg   = lane >> 4;
    const int brow = blockIdx.y, bcol = blockIdx.x, batch = blockIdx.z;

    __shared__ unsigned short lA[128][72];
    __shared__ unsigned short lB[128][72];
    __shared__ int offA[128];
    __shared__ int offB[128];

    if (tid < 128) {
        int r = brow * 128 + tid;
        int off;
        if (MODE == 0) {
            int b = r / 288, rem = r % 288;
            int h = rem / 12, j = rem % 12;
            off = ((b * 8 + batch) * 576 + h * 24 + 12 + j) * 768;
        } else {
            off = (r < M) ? (batch * 576 + r) * 768 : -1;
        }
        offA[tid] = off;
    } else {
        int c = bcol * 128 + (tid - 128);
        int off;
        if (MODE == 0) {
            int b = c / 288, rem = c % 288;
            int h = rem / 12, j = rem % 12;
            off = ((b * 8 + ((batch + 1) & 7)) * 576 + h * 24 + j) * 768;
        } else {
            off = (c < M) ? (batch * 576 + c) * 768 : -1;
        }
        offB[tid - 128] = off;
    }
    __syncthreads();

    f32x4_t acc[4][4];
#pragma unroll
    for (int i = 0; i < 4; ++i)
#pragma unroll
        for (int j = 0; j < 4; ++j) acc[i][j] = (f32x4_t){0.f, 0.f, 0.f, 0.f};

    for (int kt = 0; kt < 12; ++kt) {
        const int k0 = kt * 64;
#pragma unroll
        for (int rr = 0; rr < 8; ++rr) {
            int f   = tid + (rr << 8);
            int row = f >> 4;
            int c4  = f & 15;
            int oA = offA[row], oB = offB[row];
            float4 va = make_float4(0.f, 0.f, 0.f, 0.f);
            float4 vb = make_float4(0.f, 0.f, 0.f, 0.f);
            if (oA >= 0) va = *(const float4*)(z1 + oA + k0 + (c4 << 2));
            if (oB >= 0) vb = *(const float4*)(z2 + oB + k0 + (c4 << 2));
            ushort4 sa, sb;
            sa.x = f2bf(va.x); sa.y = f2bf(va.y); sa.z = f2bf(va.z); sa.w = f2bf(va.w);
            sb.x = f2bf(vb.x); sb.y = f2bf(vb.y); sb.z = f2bf(vb.z); sb.w = f2bf(vb.w);
            *(ushort4*)&lA[row][c4 << 2] = sa;
            *(ushort4*)&lB[row][c4 << 2] = sb;
        }
        __syncthreads();
#pragma unroll
        for (int kk = 0; kk < 64; kk += 32) {
            bf16x8_t av[4], bv[4];
#pragma unroll
            for (int i = 0; i < 4; ++i) {
                av[i] = *(const bf16x8_t*)&lA[wM * 64 + i * 16 + lr][kk + lg * 8];
                bv[i] = *(const bf16x8_t*)&lB[wN * 64 + i * 16 + lr][kk + lg * 8];
            }
#pragma unroll
            for (int i = 0; i < 4; ++i)
#pragma unroll
                for (int j = 0; j < 4; ++j)
                    acc[i][j] = __builtin_amdgcn_mfma_f32_16x16x32_bf16(
                        av[i], bv[j], acc[i][j], 0, 0, 0);
        }
        __syncthreads();
    }

    const int rowbase = brow * 128 + wM * 64;
    const int colbase = bcol * 128 + wN * 64;
    float colacc[4] = {0.f, 0.f, 0.f, 0.f};
#pragma unroll
    for (int i = 0; i < 4; ++i) {
#pragma unroll
        for (int reg = 0; reg < 4; ++reg) {
            int row = rowbase + i * 16 + lg * 4 + reg;
            bool rv = row < M;
            float rp = 0.f;
#pragma unroll
            for (int j = 0; j < 4; ++j) {
                int col = colbase + j * 16 + lr;
                float L = acc[i][j][reg] * inv_tau;
                float e = (rv && (col < M)) ? __expf(L) : 0.f;
                rp += e;
                colacc[j] += e;
                if (rv && row == col) diag[batch * M + row] = L;
            }
#pragma unroll
            for (int s = 1; s < 16; s <<= 1) rp += __shfl_xor(rp, s);
            if (lr == 0 && rv) atomicAdd(&rowsum[batch * M + row], rp);
        }
    }
#pragma unroll
    for (int j = 0; j < 4; ++j) {
        float c = colacc[j];
        c += __shfl_xor(c, 16);
        c += __shfl_xor(c, 32);
        int col = colbase + j * 16 + lr;
        if (lg == 0 && col < M) atomicAdd(&colsum[batch * M + col], c);
    }
}

__global__ void finalize_kernel(const float* __restrict__ ws, float* __restrict__ out) {
    const float* rs_ov = ws;
    const float* cs_ov = ws + 18432;
    const float* dg_ov = ws + 36864;
    const float* rs_t  = ws + 55296;
    const float* cs_t  = ws + 92160;
    const float* dg_t  = ws + 129024;
    float s_ov = 0.f, s_t = 0.f;
    for (int i = threadIdx.x; i < 18432; i += 256)
        s_ov += logf(rs_ov[i]) + logf(cs_ov[i]) - 2.f * dg_ov[i];
    for (int i = threadIdx.x; i < 36864; i += 256)
        s_t += logf(rs_t[i]) + logf(cs_t[i]) - 2.f * dg_t[i];
#pragma unroll
    for (int s = 1; s < 64; s <<= 1) {
        s_ov += __shfl_xor(s_ov, s);
        s_t  += __shfl_xor(s_t, s);
    }
    __shared__ float red[2][4];
    int w = threadIdx.x >> 6;
    if ((threadIdx.x & 63) == 0) { red[0][w] = s_ov; red[1][w] = s_t; }
    __syncthreads();
    if (threadIdx.x == 0) {
        float a = red[0][0] + red[0][1] + red[0][2] + red[0][3];
        float b = red[1][0] + red[1][1] + red[1][2] + red[1][3];
        out[0] = 0.5f * a / 18432.f + 0.05f * b / 36864.f;
    }
}

extern "C" void kernel_launch(void* const* d_in, const int* in_sizes, int n_in,
                              void* d_out, int out_size, void* d_ws, size_t ws_size,
                              hipStream_t stream) {
    const float* z1 = (const float*)d_in[0];
    const float* z2 = (const float*)d_in[1];
    float* out = (float*)d_out;
    float* ws  = (float*)d_ws;

    const size_t N_ELEM = (size_t)64 * 576 * 768;
    const size_t ACC_B  = 165888 * sizeof(float);
    const size_t BF_B   = N_ELEM * 2;
    const size_t NEED   = ACC_B + 2 * BF_B;

    hipMemsetAsync(d_ws, 0, ACC_B, stream);
    dim3 blk256(256, 1, 1);

    if (ws_size >= NEED) {
        unsigned short* z1b = (unsigned short*)((char*)d_ws + ACC_B);
        unsigned short* z2b = z1b + N_ELEM;
        int n8 = (int)(N_ELEM / 8);
        f32_to_bf16_2<<<2048, blk256, 0, stream>>>(z1, z2, z1b, z2b, n8);
        gemm128_lse_all<<<4192, blk256, 0, stream>>>(z1b, z2b, ws);
    } else {
        fused_gemm_lse<0><<<dim3(18, 18, 8), blk256, 0, stream>>>(
            z1, z2, ws, ws + 18432, ws + 36864);
        fused_gemm_lse<1><<<dim3(5, 5, 64), blk256, 0, stream>>>(
            z1, z2, ws + 55296, ws + 92160, ws + 129024);
    }
    finalize_kernel<<<1, 256, 0, stream>>>(ws, out);
}

// Round 9
// 273.825 us; speedup vs baseline: 1.0634x; 1.0202x over previous
//
#include <hip/hip_runtime.h>
#include <hip/hip_bf16.h>

typedef __attribute__((ext_vector_type(8))) short bf16x8_t;
typedef __attribute__((ext_vector_type(4))) float f32x4_t;
typedef __attribute__((ext_vector_type(8))) unsigned short u16x8_t;

__device__ inline unsigned short f2bf(float x) {
    union { float f; unsigned int u; } v; v.f = x;
    unsigned int r = v.u + 0x7FFFu + ((v.u >> 16) & 1u);
    return (unsigned short)(r >> 16);
}

__device__ inline void gl_lds16(const void* g, void* l) {
    __builtin_amdgcn_global_load_lds(
        (const __attribute__((address_space(1))) void*)g,
        (__attribute__((address_space(3))) void*)l, 16, 0, 0);
}

// ------------- f32 -> bf16 convert; branch-free grid halves ----------------
__global__ __launch_bounds__(256) void f32_to_bf16_2(
    const float* __restrict__ za, const float* __restrict__ zb,
    unsigned short* __restrict__ da, unsigned short* __restrict__ db, int n8) {
    const int half = gridDim.x >> 1;
    const bool lo = blockIdx.x < half;
    const float* __restrict__ s = lo ? za : zb;
    unsigned short* __restrict__ d = lo ? da : db;
    const int b0 = lo ? blockIdx.x : blockIdx.x - half;
    const int stride = half * blockDim.x;
    for (int i = b0 * blockDim.x + threadIdx.x; i < n8; i += stride) {
        const float4* p = (const float4*)(s + (size_t)i * 8);
        float4 a = p[0], b = p[1];
        u16x8_t v;
        v[0] = f2bf(a.x); v[1] = f2bf(a.y); v[2] = f2bf(a.z); v[3] = f2bf(a.w);
        v[4] = f2bf(b.x); v[5] = f2bf(b.y); v[6] = f2bf(b.z); v[7] = f2bf(b.w);
        *(u16x8_t*)(d + (size_t)i * 8) = v;
    }
}

// ---- merged 128x128-tile GEMM+LSE, m97 structure: BK=64, single buffer ----
// blocks (after XCD swizzle): lb 0..2591 overlap (18x18x8), 2592..4191 tile
// (5x5x64, 640-padded). LDS: A[128][64] at 0, B[128][64] at 8192 (ushorts)
// = 32 KB single buffer -> 4 blocks/CU; sibling blocks cover the vmcnt(0)
// drain (m114 implicit overlap — the mechanism behind m97's 874 TF).
// Staging: 8 gl_lds/wave, each = 8 FULL 128B lines (row = 128B).
// Swizzle: 16B-chunk phys = logical ^ (row&7); inverse on global source,
// forward on ds_read, linear LDS dest (rule 21; R7-verified 0 conflicts).
// ws float layout:
// [0) rs_ov 18432 | [18432) cs_ov 18432 | [36864) dg_ov 18432
// [55296) rs_t 36864 | [92160) cs_t 36864 | [129024) dg_t 36864 -> 165888
__global__ __launch_bounds__(256, 4) void gemm128_lse_all(
    const unsigned short* __restrict__ z1b, const unsigned short* __restrict__ z2b,
    float* __restrict__ ws) {
    const int tid  = threadIdx.x;
    const int lane = tid & 63;
    const int w    = tid >> 6;        // 0..3
    const int wM   = w >> 1;          // 0..1 (rows: wM*64)
    const int wN   = w & 1;           // 0..1 (cols: wN*64)
    const int lr   = lane & 15;
    const int lg   = lane >> 4;       // 0..3

    // T1: XCD-aware bijective swizzle over 4192 = 8*524 blocks
    const int bid = blockIdx.x;
    const int lb  = (bid & 7) * 524 + (bid >> 3);

    int M, TM, batch, rem;
    float inv_tau;
    float *rs, *cs, *dg;
    bool ov = (lb < 2592);
    if (ov) {
        M = 2304; TM = 18; inv_tau = 1.0f / 0.07f;
        rs = ws; cs = ws + 18432; dg = ws + 36864;
        batch = lb / 324; rem = lb - batch * 324;
    } else {
        M = 576; TM = 5; inv_tau = 1.0f / 0.2f;
        rs = ws + 55296; cs = ws + 92160; dg = ws + 129024;
        int tl = lb - 2592;
        batch = tl / 25; rem = tl - batch * 25;
    }
    const int brow = rem / TM;
    const int bcol = rem - brow * TM;

    __shared__ unsigned short smem[16384];   // A[128][64] + B[128][64], 32 KiB
    __shared__ int offA[128], offB[128];

    if (tid < 128) {
        int r = brow * 128 + tid;
        int off;
        if (ov) {
            int b = r / 288, rm = r % 288, h = rm / 12, j = rm % 12;
            off = ((b * 8 + batch) * 576 + h * 24 + 12 + j) * 768;
        } else {
            off = ((r < M) ? (batch * 576 + r) : (batch * 576)) * 768;
        }
        offA[tid] = off;
    } else {
        int c = bcol * 128 + (tid - 128);
        int off;
        if (ov) {
            int b = c / 288, rm = c % 288, h = rm / 12, j = rm % 12;
            off = ((b * 8 + ((batch + 1) & 7)) * 576 + h * 24 + j) * 768;
        } else {
            off = ((c < M) ? (batch * 576 + c) : (batch * 576)) * 768;
        }
        offB[tid - 128] = off;
    }
    __syncthreads();

    // staging: wave w covers A rows [w*32, w*32+32) via 4 gl_lds (8 rows each:
    // lane>>3 = row-in-group, lane&7 = phys chunk); source fetches logical
    // chunk (lane&7)^(row&7) with row&7 == lane>>3. Same for B. Dest linear.
    const int lrow8 = lane >> 3;
    const int cswz  = (((lane & 7) ^ lrow8) << 3);
    int sA[4], sB[4];
#pragma unroll
    for (int ra = 0; ra < 4; ++ra) {
        sA[ra] = offA[w * 32 + ra * 8 + lrow8] + cswz;
        sB[ra] = offB[w * 32 + ra * 8 + lrow8] + cswz;
    }

    // swizzled read offsets: half h (k = h*32..h*32+31), logical chunk h*4+lg,
    // phys = logical ^ (row&7), row&7 == lr&7. (ushort units)
    int aoff[2][4], boff[2][4];
#pragma unroll
    for (int h = 0; h < 2; ++h) {
#pragma unroll
        for (int i = 0; i < 4; ++i) {
            int ra = wM * 64 + i * 16 + lr;
            aoff[h][i] = ra * 64 + (((h * 4 + lg) ^ (ra & 7)) << 3);
            int rb = wN * 64 + i * 16 + lr;
            boff[h][i] = 8192 + rb * 64 + (((h * 4 + lg) ^ (rb & 7)) << 3);
        }
    }

    f32x4_t acc[4][4];
#pragma unroll
    for (int i = 0; i < 4; ++i)
#pragma unroll
        for (int j = 0; j < 4; ++j) acc[i][j] = (f32x4_t){0.f, 0.f, 0.f, 0.f};

#pragma unroll 2
    for (int t = 0; t < 12; ++t) {
        const int k0 = t * 64;
        // stage tile t (full 128B lines)
#pragma unroll
        for (int ra = 0; ra < 4; ++ra) {
            gl_lds16(z1b + sA[ra] + k0, &smem[(w * 32 + ra * 8) * 64]);
            gl_lds16(z2b + sB[ra] + k0, &smem[8192 + (w * 32 + ra * 8) * 64]);
        }
        asm volatile("s_waitcnt vmcnt(0)" ::: "memory");
        __syncthreads();
        // compute: 16 ds_read_b128 + 32 MFMA; compiler interleaves halves.
#pragma unroll
        for (int h = 0; h < 2; ++h) {
            bf16x8_t av[4], bv[4];
#pragma unroll
            for (int i = 0; i < 4; ++i) av[i] = *(const bf16x8_t*)&smem[aoff[h][i]];
#pragma unroll
            for (int j = 0; j < 4; ++j) bv[j] = *(const bf16x8_t*)&smem[boff[h][j]];
            __builtin_amdgcn_s_setprio(1);
#pragma unroll
            for (int i = 0; i < 4; ++i)
#pragma unroll
                for (int j = 0; j < 4; ++j)
                    acc[i][j] = __builtin_amdgcn_mfma_f32_16x16x32_bf16(
                        av[i], bv[j], acc[i][j], 0, 0, 0);
            __builtin_amdgcn_s_setprio(0);
        }
        __syncthreads();
    }

    // Epilogue: L = acc*inv_tau; exp row/col partial sums; diag.
    const int rowbase = brow * 128 + wM * 64;
    const int colbase = bcol * 128 + wN * 64;
    float colacc[4] = {0.f, 0.f, 0.f, 0.f};
#pragma unroll
    for (int i = 0; i < 4; ++i) {
#pragma unroll
        for (int reg = 0; reg < 4; ++reg) {
            int row = rowbase + i * 16 + lg * 4 + reg;
            bool rv = row < M;
            float rp = 0.f;
#pragma unroll
            for (int j = 0; j < 4; ++j) {
                int col = colbase + j * 16 + lr;
                float L = acc[i][j][reg] * inv_tau;
                float e = (rv && (col < M)) ? __expf(L) : 0.f;
                rp += e;
                colacc[j] += e;
                if (rv && row == col) dg[batch * M + row] = L;
            }
#pragma unroll
            for (int s = 1; s < 16; s <<= 1) rp += __shfl_xor(rp, s);
            if (lr == 0 && rv) atomicAdd(&rs[batch * M + row], rp);
        }
    }
#pragma unroll
    for (int j = 0; j < 4; ++j) {
        float cv = colacc[j];
        cv += __shfl_xor(cv, 16);
        cv += __shfl_xor(cv, 32);
        int col = colbase + j * 16 + lr;
        if (lg == 0 && col < M) atomicAdd(&cs[batch * M + col], cv);
    }
}

// ---------------- fallback path (R1, convert-in-flight, verified) ----------
template <int MODE>
__global__ __launch_bounds__(256) void fused_gemm_lse(
    const float* __restrict__ z1, const float* __restrict__ z2,
    float* __restrict__ rowsum, float* __restrict__ colsum,
    float* __restrict__ diag) {
    constexpr int M = (MODE == 0) ? 2304 : 576;
    constexpr float inv_tau = (MODE == 0) ? (1.0f / 0.07f) : (1.0f / 0.2f);

    const int tid  = threadIdx.x;
    const int lane = tid & 63;
    const int w    = tid >> 6;
    const int wM   = w >> 1;
    const int wN   = w & 1;
    const int lr   = lane & 15;
    const int lg   = lane >> 4;
    const int brow = blockIdx.y, bcol = blockIdx.x, batch = blockIdx.z;

    __shared__ unsigned short lA[128][72];
    __shared__ unsigned short lB[128][72];
    __shared__ int offA[128];
    __shared__ int offB[128];

    if (tid < 128) {
        int r = brow * 128 + tid;
        int off;
        if (MODE == 0) {
            int b = r / 288, rem = r % 288;
            int h = rem / 12, j = rem % 12;
            off = ((b * 8 + batch) * 576 + h * 24 + 12 + j) * 768;
        } else {
            off = (r < M) ? (batch * 576 + r) * 768 : -1;
        }
        offA[tid] = off;
    } else {
        int c = bcol * 128 + (tid - 128);
        int off;
        if (MODE == 0) {
            int b = c / 288, rem = c % 288;
            int h = rem / 12, j = rem % 12;
            off = ((b * 8 + ((batch + 1) & 7)) * 576 + h * 24 + j) * 768;
        } else {
            off = (c < M) ? (batch * 576 + c) * 768 : -1;
        }
        offB[tid - 128] = off;
    }
    __syncthreads();

    f32x4_t acc[4][4];
#pragma unroll
    for (int i = 0; i < 4; ++i)
#pragma unroll
        for (int j = 0; j < 4; ++j) acc[i][j] = (f32x4_t){0.f, 0.f, 0.f, 0.f};

    for (int kt = 0; kt < 12; ++kt) {
        const int k0 = kt * 64;
#pragma unroll
        for (int rr = 0; rr < 8; ++rr) {
            int f   = tid + (rr << 8);
            int row = f >> 4;
            int c4  = f & 15;
            int oA = offA[row], oB = offB[row];
            float4 va = make_float4(0.f, 0.f, 0.f, 0.f);
            float4 vb = make_float4(0.f, 0.f, 0.f, 0.f);
            if (oA >= 0) va = *(const float4*)(z1 + oA + k0 + (c4 << 2));
            if (oB >= 0) vb = *(const float4*)(z2 + oB + k0 + (c4 << 2));
            ushort4 sa, sb;
            sa.x = f2bf(va.x); sa.y = f2bf(va.y); sa.z = f2bf(va.z); sa.w = f2bf(va.w);
            sb.x = f2bf(vb.x); sb.y = f2bf(vb.y); sb.z = f2bf(vb.z); sb.w = f2bf(vb.w);
            *(ushort4*)&lA[row][c4 << 2] = sa;
            *(ushort4*)&lB[row][c4 << 2] = sb;
        }
        __syncthreads();
#pragma unroll
        for (int kk = 0; kk < 64; kk += 32) {
            bf16x8_t av[4], bv[4];
#pragma unroll
            for (int i = 0; i < 4; ++i) {
                av[i] = *(const bf16x8_t*)&lA[wM * 64 + i * 16 + lr][kk + lg * 8];
                bv[i] = *(const bf16x8_t*)&lB[wN * 64 + i * 16 + lr][kk + lg * 8];
            }
#pragma unroll
            for (int i = 0; i < 4; ++i)
#pragma unroll
                for (int j = 0; j < 4; ++j)
                    acc[i][j] = __builtin_amdgcn_mfma_f32_16x16x32_bf16(
                        av[i], bv[j], acc[i][j], 0, 0, 0);
        }
        __syncthreads();
    }

    const int rowbase = brow * 128 + wM * 64;
    const int colbase = bcol * 128 + wN * 64;
    float colacc[4] = {0.f, 0.f, 0.f, 0.f};
#pragma unroll
    for (int i = 0; i < 4; ++i) {
#pragma unroll
        for (int reg = 0; reg < 4; ++reg) {
            int row = rowbase + i * 16 + lg * 4 + reg;
            bool rv = row < M;
            float rp = 0.f;
#pragma unroll
            for (int j = 0; j < 4; ++j) {
                int col = colbase + j * 16 + lr;
                float L = acc[i][j][reg] * inv_tau;
                float e = (rv && (col < M)) ? __expf(L) : 0.f;
                rp += e;
                colacc[j] += e;
                if (rv && row == col) diag[batch * M + row] = L;
            }
#pragma unroll
            for (int s = 1; s < 16; s <<= 1) rp += __shfl_xor(rp, s);
            if (lr == 0 && rv) atomicAdd(&rowsum[batch * M + row], rp);
        }
    }
#pragma unroll
    for (int j = 0; j < 4; ++j) {
        float c = colacc[j];
        c += __shfl_xor(c, 16);
        c += __shfl_xor(c, 32);
        int col = colbase + j * 16 + lr;
        if (lg == 0 && col < M) atomicAdd(&colsum[batch * M + col], c);
    }
}

__global__ void finalize_kernel(const float* __restrict__ ws, float* __restrict__ out) {
    const float* rs_ov = ws;
    const float* cs_ov = ws + 18432;
    const float* dg_ov = ws + 36864;
    const float* rs_t  = ws + 55296;
    const float* cs_t  = ws + 92160;
    const float* dg_t  = ws + 129024;
    float s_ov = 0.f, s_t = 0.f;
    for (int i = threadIdx.x; i < 18432; i += 256)
        s_ov += logf(rs_ov[i]) + logf(cs_ov[i]) - 2.f * dg_ov[i];
    for (int i = threadIdx.x; i < 36864; i += 256)
        s_t += logf(rs_t[i]) + logf(cs_t[i]) - 2.f * dg_t[i];
#pragma unroll
    for (int s = 1; s < 64; s <<= 1) {
        s_ov += __shfl_xor(s_ov, s);
        s_t  += __shfl_xor(s_t, s);
    }
    __shared__ float red[2][4];
    int w = threadIdx.x >> 6;
    if ((threadIdx.x & 63) == 0) { red[0][w] = s_ov; red[1][w] = s_t; }
    __syncthreads();
    if (threadIdx.x == 0) {
        float a = red[0][0] + red[0][1] + red[0][2] + red[0][3];
        float b = red[1][0] + red[1][1] + red[1][2] + red[1][3];
        out[0] = 0.5f * a / 18432.f + 0.05f * b / 36864.f;
    }
}

extern "C" void kernel_launch(void* const* d_in, const int* in_sizes, int n_in,
                              void* d_out, int out_size, void* d_ws, size_t ws_size,
                              hipStream_t stream) {
    const float* z1 = (const float*)d_in[0];
    const float* z2 = (const float*)d_in[1];
    float* out = (float*)d_out;
    float* ws  = (float*)d_ws;

    const size_t N_ELEM = (size_t)64 * 576 * 768;
    const size_t ACC_B  = 165888 * sizeof(float);
    const size_t BF_B   = N_ELEM * 2;
    const size_t NEED   = ACC_B + 2 * BF_B;

    hipMemsetAsync(d_ws, 0, ACC_B, stream);
    dim3 blk256(256, 1, 1);

    if (ws_size >= NEED) {
        unsigned short* z1b = (unsigned short*)((char*)d_ws + ACC_B);
        unsigned short* z2b = z1b + N_ELEM;
        int n8 = (int)(N_ELEM / 8);
        f32_to_bf16_2<<<4096, blk256, 0, stream>>>(z1, z2, z1b, z2b, n8);
        gemm128_lse_all<<<4192, blk256, 0, stream>>>(z1b, z2b, ws);
    } else {
        fused_gemm_lse<0><<<dim3(18, 18, 8), blk256, 0, stream>>>(
            z1, z2, ws, ws + 18432, ws + 36864);
        fused_gemm_lse<1><<<dim3(5, 5, 64), blk256, 0, stream>>>(
            z1, z2, ws + 55296, ws + 92160, ws + 129024);
    }
    finalize_kernel<<<1, 256, 0, stream>>>(ws, out);
}

// Round 10
// 231.399 us; speedup vs baseline: 1.2583x; 1.1833x over previous
//
#include <hip/hip_runtime.h>
#include <hip/hip_bf16.h>

typedef __attribute__((ext_vector_type(8))) short bf16x8_t;
typedef __attribute__((ext_vector_type(4))) float f32x4_t;
typedef __attribute__((ext_vector_type(8))) unsigned short u16x8_t;

__device__ inline unsigned short bfr(float f) {
    __hip_bfloat16 h = __float2bfloat16(f);   // RNE
    return *reinterpret_cast<unsigned short*>(&h);
}

__device__ inline u16x8_t cvt8(float4 x, float4 y) {
    u16x8_t v;
    v[0] = bfr(x.x); v[1] = bfr(x.y); v[2] = bfr(x.z); v[3] = bfr(x.w);
    v[4] = bfr(y.x); v[5] = bfr(y.y); v[6] = bfr(y.z); v[7] = bfr(y.w);
    return v;
}

// ---- merged 128x128-tile GEMM+LSE, fused f32->bf16 staging (no convert
// pass). blocks (XCD-swizzled): lb 0..2591 overlap (18x18x8), 2592..4191
// tile (5x5x64, rows>=576 duplicated & masked).
// Per K64-step: reg-stage tile t+1 f32 (16 dwordx4/thread, counted reg-waits
// hide latency under compute), cvt->bf16, ds_write into single 32KB buffer;
// ds_read_b128 frags + 32 MFMA. Swizzle (R9-verified 0-conflict): 16B-chunk
// phys = logical ^ (row&7) — applied on global source addr + ds_read addr,
// LDS layout linear.
// ws float layout:
// [0) rs_ov 18432 | [18432) cs_ov 18432 | [36864) dg_ov 18432
// [55296) rs_t 36864 | [92160) cs_t 36864 | [129024) dg_t 36864 -> 165888
__global__ __launch_bounds__(256, 2) void gemm128_lse_all(
    const float* __restrict__ z1, const float* __restrict__ z2,
    float* __restrict__ ws) {
    const int tid  = threadIdx.x;
    const int lane = tid & 63;
    const int w    = tid >> 6;        // 0..3
    const int wM   = w >> 1;          // 0..1 (rows: wM*64)
    const int wN   = w & 1;           // 0..1 (cols: wN*64)
    const int lr   = lane & 15;
    const int lg   = lane >> 4;       // 0..3

    // T1: XCD-aware bijective swizzle over 4192 = 8*524 blocks
    const int bid = blockIdx.x;
    const int lb  = (bid & 7) * 524 + (bid >> 3);

    int M, TM, batch, rem;
    float inv_tau;
    float *rs, *cs, *dg;
    bool ov = (lb < 2592);
    if (ov) {
        M = 2304; TM = 18; inv_tau = 1.0f / 0.07f;
        rs = ws; cs = ws + 18432; dg = ws + 36864;
        batch = lb / 324; rem = lb - batch * 324;
    } else {
        M = 576; TM = 5; inv_tau = 1.0f / 0.2f;
        rs = ws + 55296; cs = ws + 92160; dg = ws + 129024;
        int tl = lb - 2592;
        batch = tl / 25; rem = tl - batch * 25;
    }
    const int brow = rem / TM;
    const int bcol = rem - brow * TM;

    __shared__ unsigned short smem[16384];   // A[128][64] + B[128][64], 32 KiB
    __shared__ int offA[128], offB[128];

    if (tid < 128) {
        int r = brow * 128 + tid;
        int off;
        if (ov) {
            int b = r / 288, rm = r % 288, h = rm / 12, j = rm % 12;
            off = ((b * 8 + batch) * 576 + h * 24 + 12 + j) * 768;
        } else {
            off = ((r < M) ? (batch * 576 + r) : (batch * 576)) * 768;
        }
        offA[tid] = off;
    } else {
        int c = bcol * 128 + (tid - 128);
        int off;
        if (ov) {
            int b = c / 288, rm = c % 288, h = rm / 12, j = rm % 12;
            off = ((b * 8 + ((batch + 1) & 7)) * 576 + h * 24 + j) * 768;
        } else {
            off = ((c < M) ? (batch * 576 + c) : (batch * 576)) * 768;
        }
        offB[tid - 128] = off;
    }
    __syncthreads();

    // staging: thread covers rows w*32+ra*8+(lane>>3), logical 16B-chunk
    // (lane&7)^(row&7); in f32 a chunk = 8 floats = 2 float4 loads.
    const int lrow8 = lane >> 3;
    const int cswz  = (((lane & 7) ^ lrow8) << 3);   // element offset in row
    int sA[4], sB[4], dA[4], dB[4];
#pragma unroll
    for (int ra = 0; ra < 4; ++ra) {
        sA[ra] = offA[w * 32 + ra * 8 + lrow8] + cswz;
        sB[ra] = offB[w * 32 + ra * 8 + lrow8] + cswz;
        dA[ra] = (w * 32 + ra * 8) * 64 + lane * 8;          // linear dest
        dB[ra] = 8192 + (w * 32 + ra * 8) * 64 + lane * 8;
    }

    // swizzled read offsets: K-half h, logical chunk h*4+lg, phys ^= row&7.
    int aoff[2][4], boff[2][4];
#pragma unroll
    for (int h = 0; h < 2; ++h) {
#pragma unroll
        for (int i = 0; i < 4; ++i) {
            int ra = wM * 64 + i * 16 + lr;
            aoff[h][i] = ra * 64 + (((h * 4 + lg) ^ (ra & 7)) << 3);
            int rb = wN * 64 + i * 16 + lr;
            boff[h][i] = 8192 + rb * 64 + (((h * 4 + lg) ^ (rb & 7)) << 3);
        }
    }

    f32x4_t acc[4][4];
#pragma unroll
    for (int i = 0; i < 4; ++i)
#pragma unroll
        for (int j = 0; j < 4; ++j) acc[i][j] = (f32x4_t){0.f, 0.f, 0.f, 0.f};

#define LOADT(T, fa, fb) do { \
    const int k0_ = (T) * 64; \
    _Pragma("unroll") \
    for (int ra = 0; ra < 4; ++ra) { \
        fa[2 * ra]     = *(const float4*)(z1 + sA[ra] + k0_); \
        fa[2 * ra + 1] = *(const float4*)(z1 + sA[ra] + k0_ + 4); \
        fb[2 * ra]     = *(const float4*)(z2 + sB[ra] + k0_); \
        fb[2 * ra + 1] = *(const float4*)(z2 + sB[ra] + k0_ + 4); \
    } } while (0)

#define WRT(fa, fb) do { \
    _Pragma("unroll") \
    for (int ra = 0; ra < 4; ++ra) { \
        *(u16x8_t*)&smem[dA[ra]] = cvt8(fa[2 * ra], fa[2 * ra + 1]); \
        *(u16x8_t*)&smem[dB[ra]] = cvt8(fb[2 * ra], fb[2 * ra + 1]); \
    } } while (0)

#define COMPUTE() do { \
    _Pragma("unroll") \
    for (int h = 0; h < 2; ++h) { \
        bf16x8_t av[4], bv[4]; \
        _Pragma("unroll") \
        for (int i = 0; i < 4; ++i) av[i] = *(const bf16x8_t*)&smem[aoff[h][i]]; \
        _Pragma("unroll") \
        for (int j = 0; j < 4; ++j) bv[j] = *(const bf16x8_t*)&smem[boff[h][j]]; \
        __builtin_amdgcn_s_setprio(1); \
        _Pragma("unroll") \
        for (int i = 0; i < 4; ++i) \
            _Pragma("unroll") \
            for (int j = 0; j < 4; ++j) \
                acc[i][j] = __builtin_amdgcn_mfma_f32_16x16x32_bf16( \
                    av[i], bv[j], acc[i][j], 0, 0, 0); \
        __builtin_amdgcn_s_setprio(0); \
    } } while (0)

    float4 a0[8], b0[8], a1[8], b1[8];
    LOADT(0, a0, b0);
#pragma unroll
    for (int tt = 0; tt < 6; ++tt) {
        const int t = 2 * tt;
        WRT(a0, b0);                          // cvt + ds_write tile t
        __syncthreads();                      // writes visible
        LOADT(t + 1, a1, b1);                 // t+1 flies under compute
        COMPUTE();                            // tile t
        __syncthreads();                      // reads done
        WRT(a1, b1);                          // tile t+1
        __syncthreads();
        if (t + 2 < 12) LOADT(t + 2, a0, b0);
        COMPUTE();                            // tile t+1
        __syncthreads();
    }
#undef LOADT
#undef WRT
#undef COMPUTE

    // Epilogue: L = acc*inv_tau; exp row/col partial sums; diag.
    const int rowbase = brow * 128 + wM * 64;
    const int colbase = bcol * 128 + wN * 64;
    float colacc[4] = {0.f, 0.f, 0.f, 0.f};
#pragma unroll
    for (int i = 0; i < 4; ++i) {
#pragma unroll
        for (int reg = 0; reg < 4; ++reg) {
            int row = rowbase + i * 16 + lg * 4 + reg;
            bool rv = row < M;
            float rp = 0.f;
#pragma unroll
            for (int j = 0; j < 4; ++j) {
                int col = colbase + j * 16 + lr;
                float L = acc[i][j][reg] * inv_tau;
                float e = (rv && (col < M)) ? __expf(L) : 0.f;
                rp += e;
                colacc[j] += e;
                if (rv && row == col) dg[batch * M + row] = L;
            }
#pragma unroll
            for (int s = 1; s < 16; s <<= 1) rp += __shfl_xor(rp, s);
            if (lr == 0 && rv) atomicAdd(&rs[batch * M + row], rp);
        }
    }
#pragma unroll
    for (int j = 0; j < 4; ++j) {
        float cv = colacc[j];
        cv += __shfl_xor(cv, 16);
        cv += __shfl_xor(cv, 32);
        int col = colbase + j * 16 + lr;
        if (lg == 0 && col < M) atomicAdd(&cs[batch * M + col], cv);
    }
}

// 8-block parallel finalize; out[0] pre-zeroed, one atomicAdd per block.
__global__ __launch_bounds__(256) void finalize_kernel(
    const float* __restrict__ ws, float* __restrict__ out) {
    const float* rs_ov = ws;
    const float* cs_ov = ws + 18432;
    const float* dg_ov = ws + 36864;
    const float* rs_t  = ws + 55296;
    const float* cs_t  = ws + 92160;
    const float* dg_t  = ws + 129024;
    const int g0 = blockIdx.x * blockDim.x + threadIdx.x;
    const int gs = gridDim.x * blockDim.x;
    float s_ov = 0.f, s_t = 0.f;
    for (int i = g0; i < 18432; i += gs)
        s_ov += logf(rs_ov[i]) + logf(cs_ov[i]) - 2.f * dg_ov[i];
    for (int i = g0; i < 36864; i += gs)
        s_t += logf(rs_t[i]) + logf(cs_t[i]) - 2.f * dg_t[i];
    float c = 0.5f * s_ov / 18432.f + 0.05f * s_t / 36864.f;
#pragma unroll
    for (int s = 1; s < 64; s <<= 1) c += __shfl_xor(c, s);
    __shared__ float red[4];
    int wv = threadIdx.x >> 6;
    if ((threadIdx.x & 63) == 0) red[wv] = c;
    __syncthreads();
    if (threadIdx.x == 0)
        atomicAdd(out, red[0] + red[1] + red[2] + red[3]);
}

extern "C" void kernel_launch(void* const* d_in, const int* in_sizes, int n_in,
                              void* d_out, int out_size, void* d_ws, size_t ws_size,
                              hipStream_t stream) {
    const float* z1 = (const float*)d_in[0];
    const float* z2 = (const float*)d_in[1];
    float* out = (float*)d_out;
    float* ws  = (float*)d_ws;

    const size_t ACC_B = 165888 * sizeof(float);
    hipMemsetAsync(d_ws, 0, ACC_B, stream);
    hipMemsetAsync(d_out, 0, sizeof(float), stream);

    gemm128_lse_all<<<4192, 256, 0, stream>>>(z1, z2, ws);
    finalize_kernel<<<8, 256, 0, stream>>>(ws, out);
}

// Round 11
// 194.799 us; speedup vs baseline: 1.4947x; 1.1879x over previous
//
#include <hip/hip_runtime.h>
#include <hip/hip_bf16.h>

typedef __attribute__((ext_vector_type(8))) short bf16x8_t;
typedef __attribute__((ext_vector_type(4))) float f32x4_t;
typedef __attribute__((ext_vector_type(8))) unsigned short u16x8_t;

__device__ inline unsigned short bfr(float f) {
    __hip_bfloat16 h = __float2bfloat16(f);   // RNE
    return *reinterpret_cast<unsigned short*>(&h);
}

__device__ inline u16x8_t cvt8(float4 x, float4 y) {
    u16x8_t v;
    v[0] = bfr(x.x); v[1] = bfr(x.y); v[2] = bfr(x.z); v[3] = bfr(x.w);
    v[4] = bfr(y.x); v[5] = bfr(y.y); v[6] = bfr(y.z); v[7] = bfr(y.w);
    return v;
}

// ---- merged 128x128-tile GEMM+LSE, fused f32->bf16 staging ----------------
// blocks (XCD-swizzled): lb 0..2591 overlap (8 batches x 18x18 tiles,
// SUPERTILED: rem -> sc=rem/108, brow=(rem%108)/6, bcol=sc*6+(rem%108)%6 --
// B-panels partitioned per sc-group => L2-resident, A-panels streamed 3x),
// lb 2592..4191 tile (64 batches x 5x5, rows>=576 duplicated & masked).
// Per K64-step: load f32 (A half then B half, <=96 live regs), cvt->bf16,
// ds_write 32KB single buffer, sync, 16 ds_read_b128 + 32 MFMA, sync.
// 3 blocks/CU provide the latency cover (m114 implicit overlap).
// Swizzle (verified 0-conflict): 16B-chunk phys = logical ^ (row&7) on
// global source + ds_read; LDS layout linear.
// ws float layout:
// [0) rs_ov 18432 | [18432) cs_ov 18432 | [36864) dg_ov 18432
// [55296) rs_t 36864 | [92160) cs_t 36864 | [129024) dg_t 36864 -> 165888
__global__ __launch_bounds__(256, 3) void gemm128_lse_all(
    const float* __restrict__ z1, const float* __restrict__ z2,
    float* __restrict__ ws) {
    const int tid  = threadIdx.x;
    const int lane = tid & 63;
    const int w    = tid >> 6;        // 0..3
    const int wM   = w >> 1;          // 0..1 (rows: wM*64)
    const int wN   = w & 1;           // 0..1 (cols: wN*64)
    const int lr   = lane & 15;
    const int lg   = lane >> 4;       // 0..3

    // T1: XCD-aware bijective swizzle over 4192 = 8*524 blocks
    const int bid = blockIdx.x;
    const int lb  = (bid & 7) * 524 + (bid >> 3);

    int M, batch, brow, bcol;
    float inv_tau;
    float *rs, *cs, *dg;
    bool ov = (lb < 2592);
    if (ov) {
        M = 2304; inv_tau = 1.0f / 0.07f;
        rs = ws; cs = ws + 18432; dg = ws + 36864;
        batch = lb / 324;
        int rem = lb - batch * 324;
        int sc = rem / 108, r2 = rem - sc * 108;
        brow = r2 / 6;
        bcol = sc * 6 + (r2 - brow * 6);
    } else {
        M = 576; inv_tau = 1.0f / 0.2f;
        rs = ws + 55296; cs = ws + 92160; dg = ws + 129024;
        int tl = lb - 2592;
        batch = tl / 25;
        int rem = tl - batch * 25;
        brow = rem / 5;
        bcol = rem - brow * 5;
    }

    __shared__ unsigned short smem[16384];   // A[128][64] + B[128][64], 32 KiB
    __shared__ int offA[128], offB[128];

    if (tid < 128) {
        int r = brow * 128 + tid;
        int off;
        if (ov) {
            int b = r / 288, rm = r % 288, h = rm / 12, j = rm % 12;
            off = ((b * 8 + batch) * 576 + h * 24 + 12 + j) * 768;
        } else {
            off = ((r < M) ? (batch * 576 + r) : (batch * 576)) * 768;
        }
        offA[tid] = off;
    } else {
        int c = bcol * 128 + (tid - 128);
        int off;
        if (ov) {
            int b = c / 288, rm = c % 288, h = rm / 12, j = rm % 12;
            off = ((b * 8 + ((batch + 1) & 7)) * 576 + h * 24 + j) * 768;
        } else {
            off = ((c < M) ? (batch * 576 + c) : (batch * 576)) * 768;
        }
        offB[tid - 128] = off;
    }
    __syncthreads();

    // staging: thread covers rows w*32+ra*8+(lane>>3), logical 16B-chunk
    // (lane&7)^(row&7); in f32 a chunk = 8 floats = 2 float4 loads.
    const int lrow8 = lane >> 3;
    const int cswz  = (((lane & 7) ^ lrow8) << 3);   // element offset in row
    int sA[4], sB[4], dA[4], dB[4];
#pragma unroll
    for (int ra = 0; ra < 4; ++ra) {
        sA[ra] = offA[w * 32 + ra * 8 + lrow8] + cswz;
        sB[ra] = offB[w * 32 + ra * 8 + lrow8] + cswz;
        dA[ra] = (w * 32 + ra * 8) * 64 + lane * 8;          // linear dest
        dB[ra] = 8192 + (w * 32 + ra * 8) * 64 + lane * 8;
    }

    // swizzled read offsets: K-half h, logical chunk h*4+lg, phys ^= row&7.
    int aoff[2][4], boff[2][4];
#pragma unroll
    for (int h = 0; h < 2; ++h) {
#pragma unroll
        for (int i = 0; i < 4; ++i) {
            int ra = wM * 64 + i * 16 + lr;
            aoff[h][i] = ra * 64 + (((h * 4 + lg) ^ (ra & 7)) << 3);
            int rb = wN * 64 + i * 16 + lr;
            boff[h][i] = 8192 + rb * 64 + (((h * 4 + lg) ^ (rb & 7)) << 3);
        }
    }

    f32x4_t acc[4][4];
#pragma unroll
    for (int i = 0; i < 4; ++i)
#pragma unroll
        for (int j = 0; j < 4; ++j) acc[i][j] = (f32x4_t){0.f, 0.f, 0.f, 0.f};

    for (int t = 0; t < 12; ++t) {
        const int k0 = t * 64;
        {
            float4 fa[8];
#pragma unroll
            for (int ra = 0; ra < 4; ++ra) {
                fa[2 * ra]     = *(const float4*)(z1 + sA[ra] + k0);
                fa[2 * ra + 1] = *(const float4*)(z1 + sA[ra] + k0 + 4);
            }
#pragma unroll
            for (int ra = 0; ra < 4; ++ra)
                *(u16x8_t*)&smem[dA[ra]] = cvt8(fa[2 * ra], fa[2 * ra + 1]);
        }
        {
            float4 fb[8];
#pragma unroll
            for (int ra = 0; ra < 4; ++ra) {
                fb[2 * ra]     = *(const float4*)(z2 + sB[ra] + k0);
                fb[2 * ra + 1] = *(const float4*)(z2 + sB[ra] + k0 + 4);
            }
#pragma unroll
            for (int ra = 0; ra < 4; ++ra)
                *(u16x8_t*)&smem[dB[ra]] = cvt8(fb[2 * ra], fb[2 * ra + 1]);
        }
        __syncthreads();
#pragma unroll
        for (int h = 0; h < 2; ++h) {
            bf16x8_t av[4], bv[4];
#pragma unroll
            for (int i = 0; i < 4; ++i) av[i] = *(const bf16x8_t*)&smem[aoff[h][i]];
#pragma unroll
            for (int j = 0; j < 4; ++j) bv[j] = *(const bf16x8_t*)&smem[boff[h][j]];
            __builtin_amdgcn_s_setprio(1);
#pragma unroll
            for (int i = 0; i < 4; ++i)
#pragma unroll
                for (int j = 0; j < 4; ++j)
                    acc[i][j] = __builtin_amdgcn_mfma_f32_16x16x32_bf16(
                        av[i], bv[j], acc[i][j], 0, 0, 0);
            __builtin_amdgcn_s_setprio(0);
        }
        __syncthreads();
    }

    // Epilogue: L = acc*inv_tau; exp row/col partial sums; diag.
    const int rowbase = brow * 128 + wM * 64;
    const int colbase = bcol * 128 + wN * 64;
    float colacc[4] = {0.f, 0.f, 0.f, 0.f};
#pragma unroll
    for (int i = 0; i < 4; ++i) {
#pragma unroll
        for (int reg = 0; reg < 4; ++reg) {
            int row = rowbase + i * 16 + lg * 4 + reg;
            bool rv = row < M;
            float rp = 0.f;
#pragma unroll
            for (int j = 0; j < 4; ++j) {
                int col = colbase + j * 16 + lr;
                float L = acc[i][j][reg] * inv_tau;
                float e = (rv && (col < M)) ? __expf(L) : 0.f;
                rp += e;
                colacc[j] += e;
                if (rv && row == col) dg[batch * M + row] = L;
            }
#pragma unroll
            for (int s = 1; s < 16; s <<= 1) rp += __shfl_xor(rp, s);
            if (lr == 0 && rv) atomicAdd(&rs[batch * M + row], rp);
        }
    }
#pragma unroll
    for (int j = 0; j < 4; ++j) {
        float cv = colacc[j];
        cv += __shfl_xor(cv, 16);
        cv += __shfl_xor(cv, 32);
        int col = colbase + j * 16 + lr;
        if (lg == 0 && col < M) atomicAdd(&cs[batch * M + col], cv);
    }
}

// 8-block parallel finalize; out[0] pre-zeroed, one atomicAdd per block.
__global__ __launch_bounds__(256) void finalize_kernel(
    const float* __restrict__ ws, float* __restrict__ out) {
    const float* rs_ov = ws;
    const float* cs_ov = ws + 18432;
    const float* dg_ov = ws + 36864;
    const float* rs_t  = ws + 55296;
    const float* cs_t  = ws + 92160;
    const float* dg_t  = ws + 129024;
    const int g0 = blockIdx.x * blockDim.x + threadIdx.x;
    const int gs = gridDim.x * blockDim.x;
    float s_ov = 0.f, s_t = 0.f;
    for (int i = g0; i < 18432; i += gs)
        s_ov += logf(rs_ov[i]) + logf(cs_ov[i]) - 2.f * dg_ov[i];
    for (int i = g0; i < 36864; i += gs)
        s_t += logf(rs_t[i]) + logf(cs_t[i]) - 2.f * dg_t[i];
    float c = 0.5f * s_ov / 18432.f + 0.05f * s_t / 36864.f;
#pragma unroll
    for (int s = 1; s < 64; s <<= 1) c += __shfl_xor(c, s);
    __shared__ float red[4];
    int wv = threadIdx.x >> 6;
    if ((threadIdx.x & 63) == 0) red[wv] = c;
    __syncthreads();
    if (threadIdx.x == 0)
        atomicAdd(out, red[0] + red[1] + red[2] + red[3]);
}

extern "C" void kernel_launch(void* const* d_in, const int* in_sizes, int n_in,
                              void* d_out, int out_size, void* d_ws, size_t ws_size,
                              hipStream_t stream) {
    const float* z1 = (const float*)d_in[0];
    const float* z2 = (const float*)d_in[1];
    float* out = (float*)d_out;
    float* ws  = (float*)d_ws;

    const size_t ACC_B = 165888 * sizeof(float);
    hipMemsetAsync(d_ws, 0, ACC_B, stream);
    hipMemsetAsync(d_out, 0, sizeof(float), stream);

    gemm128_lse_all<<<4192, 256, 0, stream>>>(z1, z2, ws);
    finalize_kernel<<<8, 256, 0, stream>>>(ws, out);
}